// Round 9
// baseline (70.538 us; speedup 1.0000x reference)
//
#include <hip/hip_runtime.h>

#define B_ 8
#define N_ 1024
#define CIN_ 256
#define COUT_ 512
#define H_ 8
#define DH_ 64

typedef __attribute__((ext_vector_type(8))) short bf8;
typedef __attribute__((ext_vector_type(4))) short s4;
typedef __attribute__((ext_vector_type(4))) float f4;
typedef __attribute__((ext_vector_type(2))) unsigned int u2;

__device__ __forceinline__ short f2bf(float f) {
  unsigned u = __builtin_bit_cast(unsigned, f);
  u += 0x7fffu + ((u >> 16) & 1u);
  return (short)(u >> 16);
}
__device__ __forceinline__ float bf2f(short s) {
  unsigned u = ((unsigned)(unsigned short)s) << 16;
  return __builtin_bit_cast(float, u);
}

#if __has_builtin(__builtin_amdgcn_exp2f)
#define EXP2 __builtin_amdgcn_exp2f
#else
#define EXP2 exp2f
#endif

__device__ __forceinline__ unsigned cvtpk(float a, float b) {
  unsigned u;
  asm("v_cvt_pk_bf16_f32 %0, %1, %2" : "=v"(u) : "v"(a), "v"(b));
  return u;
}

#define MFMA16(a, b, c) __builtin_amdgcn_mfma_f32_16x16x32_bf16((a), (b), (c), 0, 0, 0)

// async 16B global->LDS (linear dest: wave-uniform base + lane*16)
#define GLD16(gp, lp)                                                              \
  __builtin_amdgcn_global_load_lds((const __attribute__((address_space(1))) void*)(gp), \
                                   (__attribute__((address_space(3))) void*)(lp), 16, 0, 0)

// ---- prep: Wt[2048][256] bf16 weight panel (Q|K|V|conv) + x cast, fused ----
__global__ void k_prep(const float* __restrict__ Wq, const float* __restrict__ Wk,
                       const float* __restrict__ Wv, const float* __restrict__ Cw,
                       const float* __restrict__ x, short* __restrict__ Wt,
                       short* __restrict__ xb) {
  int blk = blockIdx.x;
  if (blk < 2048) {
    int col = blk;
    int k = threadIdx.x;
    float v;
    if (col < 512) {
      int h = col >> 6, d = col & 63;
      v = Wq[(h * CIN_ + k) * DH_ + d];
    } else if (col < 1024) {
      int c = col - 512, h = c >> 6, d = c & 63;
      v = Wk[(h * CIN_ + k) * DH_ + d];
    } else if (col < 1536) {
      int c = col - 1024, h = c >> 6, d = c & 63;
      v = Wv[(h * CIN_ + k) * DH_ + d];
    } else {
      v = Cw[(col - 1536) * CIN_ + k];
    }
    Wt[col * CIN_ + k] = f2bf(v);
  } else {
    int i = (blk - 2048) * 256 + threadIdx.x;
    f4 a = *reinterpret_cast<const f4*>(x + (size_t)i * 8);
    f4 b = *reinterpret_cast<const f4*>(x + (size_t)i * 8 + 4);
    bf8 o;
    o[0] = f2bf(a[0]); o[1] = f2bf(a[1]); o[2] = f2bf(a[2]); o[3] = f2bf(a[3]);
    o[4] = f2bf(b[0]); o[5] = f2bf(b[1]); o[6] = f2bf(b[2]); o[7] = f2bf(b[3]);
    *reinterpret_cast<bf8*>(xb + (size_t)i * 8) = o;
  }
}

// ---- GEMM: [8192x256] x [256x2048], 128x128 tile, BK=64, global_load_lds dbuf staging,
//      counted vmcnt + raw barriers, XOR-swizzled LDS.
//      Outputs: Q*scale, K ([B][H][N][64]), Vt ([B][H][64][N]), proj bf16 ----
__global__ __launch_bounds__(256) void k_gemm(const short* __restrict__ xb, const short* __restrict__ Wt,
                                              short* __restrict__ Qw, short* __restrict__ Kw,
                                              short* __restrict__ Vt, short* __restrict__ Pj) {
  __shared__ short Al[2][128][64];   // 32 KB: [buf][row][k], chunk c holds global chunk c^(row&7)
  __shared__ short Bl[2][128][64];   // 32 KB
  int tid = threadIdx.x;
  int mt = blockIdx.x >> 4, nt = blockIdx.x & 15;
  int row0 = mt * 128, col0 = nt * 128;
  int w = tid >> 6, lane = tid & 63, g = lane >> 4, lr = lane & 15;
  int wm = w >> 1, wn = w & 1;
  f4 acc[4][4];
#pragma unroll
  for (int i = 0; i < 4; ++i)
#pragma unroll
    for (int j = 0; j < 4; ++j) acc[i][j] = (f4){0.f, 0.f, 0.f, 0.f};

  // staging: per matrix 1024 16B-slots/tile; thread covers slots p*256+tid (p=0..3).
  // slot s -> row s>>3, lds chunk s&7, global chunk (s&7)^(row&7).
  int srow[4], sgc[4];
#pragma unroll
  for (int p = 0; p < 4; ++p) {
    int s = p * 256 + tid;
    srow[p] = s >> 3;
    sgc[p] = (s & 7) ^ (srow[p] & 7);
  }

#define STAGE_AB(k0_, buf_)                                                     \
  {                                                                             \
    char* abase = (char*)&Al[buf_][0][0];                                       \
    char* bbase = (char*)&Bl[buf_][0][0];                                       \
    _Pragma("unroll")                                                           \
    for (int p = 0; p < 4; ++p) {                                               \
      int lb = (p * 256 + w * 64) << 4;                                         \
      GLD16(xb + (row0 + srow[p]) * CIN_ + (k0_) + sgc[p] * 8, abase + lb);     \
      GLD16(Wt + (col0 + srow[p]) * CIN_ + (k0_) + sgc[p] * 8, bbase + lb);     \
    }                                                                           \
  }

  STAGE_AB(0, 0);

  for (int kt = 0; kt < 4; ++kt) {
    int cur = kt & 1;
    if (kt < 3) {
      STAGE_AB((kt + 1) * 64, cur ^ 1);
      asm volatile("s_waitcnt vmcnt(8)" ::: "memory");  // tile kt landed; kt+1's 8 stay out
    } else {
      asm volatile("s_waitcnt vmcnt(0)" ::: "memory");
    }
    __builtin_amdgcn_s_barrier();

    const short* al = &Al[cur][0][0];
    const short* bl = &Bl[cur][0][0];
    bf8 af[4][2], bb[4][2];
#pragma unroll
    for (int mi = 0; mi < 4; ++mi) {
      int R = wm * 64 + mi * 16 + lr;
      int sw = R & 7;
      af[mi][0] = *reinterpret_cast<const bf8*>(al + R * 64 + ((g ^ sw) * 8));
      af[mi][1] = *reinterpret_cast<const bf8*>(al + R * 64 + (((4 + g) ^ sw) * 8));
    }
#pragma unroll
    for (int ni = 0; ni < 4; ++ni) {
      int R = wn * 64 + ni * 16 + lr;
      int sw = R & 7;
      bb[ni][0] = *reinterpret_cast<const bf8*>(bl + R * 64 + ((g ^ sw) * 8));
      bb[ni][1] = *reinterpret_cast<const bf8*>(bl + R * 64 + (((4 + g) ^ sw) * 8));
    }
#pragma unroll
    for (int mi = 0; mi < 4; ++mi)
#pragma unroll
      for (int ni = 0; ni < 4; ++ni) {
        acc[mi][ni] = MFMA16(af[mi][0], bb[ni][0], acc[mi][ni]);
        acc[mi][ni] = MFMA16(af[mi][1], bb[ni][1], acc[mi][ni]);
      }
    asm volatile("s_waitcnt lgkmcnt(0)" ::: "memory");
    __builtin_amdgcn_s_barrier();   // all waves done reading buf cur before it is re-staged
  }

  const float QSCL = 0.125f * 1.4426950408889634f;  // 1/sqrt(dh) * log2(e), folded into Q
#pragma unroll
  for (int mi = 0; mi < 4; ++mi)
#pragma unroll
    for (int ni = 0; ni < 4; ++ni) {
      int c = col0 + wn * 64 + ni * 16 + lr;
      int r0 = row0 + wm * 64 + mi * 16 + g * 4;
      int b = r0 >> 10, n0 = r0 & 1023;
      if (c < 1024) {
#pragma unroll
        for (int j = 0; j < 4; ++j) {
          int n = n0 + j;
          if (c < 512) {
            Qw[((b * H_ + (c >> 6)) * N_ + n) * DH_ + (c & 63)] = f2bf(acc[mi][ni][j] * QSCL);
          } else {
            int cc = c - 512;
            Kw[((b * H_ + (cc >> 6)) * N_ + n) * DH_ + (cc & 63)] = f2bf(acc[mi][ni][j]);
          }
        }
      } else if (c < 1536) {
        int cc = c - 1024;
        int hh = cc >> 6, d = cc & 63;
        s4 vv;
#pragma unroll
        for (int j = 0; j < 4; ++j) vv[j] = f2bf(acc[mi][ni][j]);
        *reinterpret_cast<s4*>(Vt + ((size_t)(b * H_ + hh) * DH_ + d) * N_ + n0) = vv;
      } else {
#pragma unroll
        for (int j = 0; j < 4; ++j) {
          Pj[(size_t)(r0 + j) * COUT_ + (c - 1536)] = f2bf(acc[mi][ni][j]);
        }
      }
    }
}

// ---- attention: block = (b,h,256 q-rows), 4 waves x 64 q (qs=4). K/V dbuf in LDS via
//      global_load_lds + counted vmcnt. Streaming softmax (no max), swapped QK.
//      Per-qs Pl buffers (no time-sharing); all P fragments are named scalars. ----
__global__ __launch_bounds__(256, 1) void k_attn(const short* __restrict__ Qw, const short* __restrict__ Kw,
                                                 const short* __restrict__ Vt, short* __restrict__ At) {
  __shared__ short Kl[2][64][64];      // 16 KB: [buf][kv][dh], chunk c holds global chunk c^(kv&7)
  __shared__ short Vl[2][64][64];      // 16 KB: [buf][dh][kv], chunk c holds global chunk c^(dh&7)
  __shared__ short Pl[4][4][16][64];   // 32 KB: per-wave, per-qs P relayout, XOR-swizzled cols
  int tid = threadIdx.x;
  // XCD swizzle: 256 blocks, 8 XCDs -> 32 consecutive nid per XCD = 8 full (b,h) groups
  int nid = ((blockIdx.x & 7) << 5) | (blockIdx.x >> 3);
  int bh = nid >> 2;
  int qb = nid & 3;
  int w = tid >> 6, lane = tid & 63, g = lane >> 4, lr = lane & 15;
  int qglob = qb * 256 + w * 64;
  const short* Qp = Qw + ((size_t)bh * N_ + qglob) * DH_;
  const short* Kp = Kw + (size_t)bh * N_ * DH_;
  const short* Vp = Vt + (size_t)bh * DH_ * N_;

  // staging geometry: 512 16B-slots per tile per matrix; slot s -> row s>>3, lds chunk s&7,
  // global chunk (s&7)^(row&7). Thread covers slots tid and tid+256.
  int sr0 = tid >> 3, sc0 = (tid & 7) ^ (sr0 & 7);
  int s1 = tid + 256;
  int sr1 = s1 >> 3, sc1 = (s1 & 7) ^ (sr1 & 7);
  int lo0 = (w * 64) << 4;           // wave-uniform LDS byte base, pass 0
  int lo1 = (w * 64 + 256) << 4;     // pass 1

  // prologue: stage tile 0 into buf 0
  {
    char* klb = (char*)&Kl[0][0][0];
    char* vlb = (char*)&Vl[0][0][0];
    GLD16(Kp + sr0 * 64 + sc0 * 8, klb + lo0);
    GLD16(Kp + sr1 * 64 + sc1 * 8, klb + lo1);
    GLD16(Vp + (size_t)sr0 * N_ + sc0 * 8, vlb + lo0);
    GLD16(Vp + (size_t)sr1 * N_ + sc1 * 8, vlb + lo1);
  }

  bf8 aq[4][2];
#pragma unroll
  for (int qs = 0; qs < 4; ++qs) {
    aq[qs][0] = *reinterpret_cast<const bf8*>(Qp + (qs * 16 + lr) * DH_ + g * 8);
    aq[qs][1] = *reinterpret_cast<const bf8*>(Qp + (qs * 16 + lr) * DH_ + 32 + g * 8);
  }

  f4 o[4][4];
  f4 lacc[4];
#pragma unroll
  for (int qs = 0; qs < 4; ++qs) {
    lacc[qs] = (f4){0.f, 0.f, 0.f, 0.f};
#pragma unroll
    for (int i = 0; i < 4; ++i) o[qs][i] = (f4){0.f, 0.f, 0.f, 0.f};
  }

  const int swz = (lr & 7) << 3;
  short* plq0 = &Pl[w][0][0][0];
  short* plq1 = &Pl[w][1][0][0];
  short* plq2 = &Pl[w][2][0][0];
  short* plq3 = &Pl[w][3][0][0];

  // per-qs: QK^T (swapped, D[kv][q]) -> exp -> pack -> write own Pl buffer
#define QS_BLOCK(qs_, pl_)                                                      \
  {                                                                             \
    f4 s_[4];                                                                   \
    _Pragma("unroll")                                                           \
    for (int kt = 0; kt < 4; ++kt) {                                            \
      f4 z = (f4){0.f, 0.f, 0.f, 0.f};                                          \
      z = MFMA16(bk0[kt], aq[qs_][0], z);                                       \
      z = MFMA16(bk1[kt], aq[qs_][1], z);                                       \
      s_[kt] = z;                                                               \
    }                                                                           \
    _Pragma("unroll")                                                           \
    for (int kt = 0; kt < 4; ++kt) {                                            \
      f4 p;                                                                     \
      p[0] = EXP2(s_[kt][0]); p[1] = EXP2(s_[kt][1]);                           \
      p[2] = EXP2(s_[kt][2]); p[3] = EXP2(s_[kt][3]);                           \
      lacc[qs_] += p;                                                           \
      u2 pk;                                                                    \
      pk[0] = cvtpk(p[0], p[1]);                                                \
      pk[1] = cvtpk(p[2], p[3]);                                                \
      *reinterpret_cast<u2*>((pl_) + lr * 64 + ((kt * 16 + g * 4) ^ swz)) = pk; \
    }                                                                           \
  }

  for (int t = 0; t < 16; ++t) {
    int cur = t & 1;
    if (t < 15) {
      // stage tile t+1 into other buffer (4 loads in flight across the barrier)
      const short* kb = Kp + (t + 1) * (64 * DH_);
      const short* vb = Vp + (t + 1) * 64;
      char* klb = (char*)&Kl[cur ^ 1][0][0];
      char* vlb = (char*)&Vl[cur ^ 1][0][0];
      GLD16(kb + sr0 * 64 + sc0 * 8, klb + lo0);
      GLD16(kb + sr1 * 64 + sc1 * 8, klb + lo1);
      GLD16(vb + (size_t)sr0 * N_ + sc0 * 8, vlb + lo0);
      GLD16(vb + (size_t)sr1 * N_ + sc1 * 8, vlb + lo1);
      asm volatile("s_waitcnt vmcnt(4)" ::: "memory");   // tile t's 4 loads done; t+1's stay out
    } else {
      asm volatile("s_waitcnt vmcnt(0)" ::: "memory");
    }
    __builtin_amdgcn_s_barrier();

    // K frags once per tile (amortized over 64 q-rows)
    const short* klc = &Kl[cur][0][0];
    bf8 bk0[4], bk1[4];
#pragma unroll
    for (int kt = 0; kt < 4; ++kt) {
      int R = kt * 16 + lr;
      const short* kr = klc + R * 64;
      int sw = (R & 7) << 3;
      bk0[kt] = *reinterpret_cast<const bf8*>(kr + ((g * 8) ^ sw));
      bk1[kt] = *reinterpret_cast<const bf8*>(kr + ((32 + g * 8) ^ sw));
    }

    QS_BLOCK(0, plq0)
    QS_BLOCK(1, plq1)
    QS_BLOCK(2, plq2)
    QS_BLOCK(3, plq3)

    asm volatile("s_waitcnt lgkmcnt(0)" ::: "memory");
    __builtin_amdgcn_sched_barrier(0);
    bf8 pa00 = *reinterpret_cast<const bf8*>(plq0 + lr * 64 + ((g * 8) ^ swz));
    bf8 pa01 = *reinterpret_cast<const bf8*>(plq0 + lr * 64 + ((32 + g * 8) ^ swz));
    bf8 pa10 = *reinterpret_cast<const bf8*>(plq1 + lr * 64 + ((g * 8) ^ swz));
    bf8 pa11 = *reinterpret_cast<const bf8*>(plq1 + lr * 64 + ((32 + g * 8) ^ swz));
    bf8 pa20 = *reinterpret_cast<const bf8*>(plq2 + lr * 64 + ((g * 8) ^ swz));
    bf8 pa21 = *reinterpret_cast<const bf8*>(plq2 + lr * 64 + ((32 + g * 8) ^ swz));
    bf8 pa30 = *reinterpret_cast<const bf8*>(plq3 + lr * 64 + ((g * 8) ^ swz));
    bf8 pa31 = *reinterpret_cast<const bf8*>(plq3 + lr * 64 + ((32 + g * 8) ^ swz));

    // V frags + PV for all 4 qs
    const short* vlc = &Vl[cur][0][0];
#pragma unroll
    for (int dt = 0; dt < 4; ++dt) {
      int R = dt * 16 + lr;
      const short* vr = vlc + R * 64;
      int sw = (R & 7) << 3;
      bf8 bv0 = *reinterpret_cast<const bf8*>(vr + ((g * 8) ^ sw));
      bf8 bv1 = *reinterpret_cast<const bf8*>(vr + ((32 + g * 8) ^ sw));
      o[0][dt] = MFMA16(pa00, bv0, o[0][dt]);
      o[0][dt] = MFMA16(pa01, bv1, o[0][dt]);
      o[1][dt] = MFMA16(pa10, bv0, o[1][dt]);
      o[1][dt] = MFMA16(pa11, bv1, o[1][dt]);
      o[2][dt] = MFMA16(pa20, bv0, o[2][dt]);
      o[2][dt] = MFMA16(pa21, bv1, o[2][dt]);
      o[3][dt] = MFMA16(pa30, bv0, o[3][dt]);
      o[3][dt] = MFMA16(pa31, bv1, o[3][dt]);
    }
    asm volatile("s_waitcnt lgkmcnt(0)" ::: "memory");
    __builtin_amdgcn_s_barrier();   // all waves done reading buf cur before it is re-staged
  }

  // l: in-lane hsum + across the 4 g-copies -> full sum over kv for q=lr
  float ls[4];
#pragma unroll
  for (int qs = 0; qs < 4; ++qs) {
    float v = (lacc[qs][0] + lacc[qs][1]) + (lacc[qs][2] + lacc[qs][3]);
    v += __shfl_xor(v, 16, 64);
    v += __shfl_xor(v, 32, 64);
    ls[qs] = v;
  }
  // redistribute: lane needs l[q=g*4+j], held (replicated) by lane g*16 + g*4 + j
  float lf[4][4];
#pragma unroll
  for (int qs = 0; qs < 4; ++qs)
#pragma unroll
    for (int j = 0; j < 4; ++j)
      lf[qs][j] = __shfl(ls[qs], (lane & 48) + ((lane & 48) >> 2) + j, 64);
  int b = bh >> 3, h = bh & 7;
#pragma unroll
  for (int qs = 0; qs < 4; ++qs)
#pragma unroll
    for (int dt = 0; dt < 4; ++dt)
#pragma unroll
      for (int j = 0; j < 4; ++j) {
        float v = fmaxf(o[qs][dt][j] / lf[qs][j], 0.f);
        int n = qglob + qs * 16 + g * 4 + j;
        At[((size_t)b * N_ + n) * COUT_ + h * DH_ + dt * 16 + lr] = f2bf(v);
      }
}

// ---- add + bias + LayerNorm, f32 out ----
__global__ __launch_bounds__(256) void k_ln(const short* __restrict__ At, const short* __restrict__ Pj,
                                            const float* __restrict__ cb, const float* __restrict__ lw,
                                            const float* __restrict__ lb, float* __restrict__ out) {
  int row = blockIdx.x * 4 + (threadIdx.x >> 6);
  int lane = threadIdx.x & 63;
  int c0 = lane * 8;
  bf8 a8 = *reinterpret_cast<const bf8*>(At + (size_t)row * COUT_ + c0);
  bf8 p8 = *reinterpret_cast<const bf8*>(Pj + (size_t)row * COUT_ + c0);
  float y[8];
  float sum = 0.f, sq = 0.f;
#pragma unroll
  for (int j = 0; j < 8; ++j) {
    float v = bf2f(a8[j]) + bf2f(p8[j]) + cb[c0 + j];
    y[j] = v;
    sum += v;
    sq += v * v;
  }
#pragma unroll
  for (int off = 1; off < 64; off <<= 1) {
    sum += __shfl_xor(sum, off, 64);
    sq += __shfl_xor(sq, off, 64);
  }
  float mean = sum * (1.f / 512.f);
  float var = sq * (1.f / 512.f) - mean * mean;
  float rstd = rsqrtf(var + 1e-5f);
  f4 o0, o1;
#pragma unroll
  for (int j = 0; j < 4; ++j) o0[j] = (y[j] - mean) * rstd * lw[c0 + j] + lb[c0 + j];
#pragma unroll
  for (int j = 0; j < 4; ++j) o1[j] = (y[4 + j] - mean) * rstd * lw[c0 + 4 + j] + lb[c0 + 4 + j];
  *reinterpret_cast<f4*>(out + (size_t)row * COUT_ + c0) = o0;
  *reinterpret_cast<f4*>(out + (size_t)row * COUT_ + c0 + 4) = o1;
}

extern "C" void kernel_launch(void* const* d_in, const int* in_sizes, int n_in,
                              void* d_out, int out_size, void* d_ws, size_t ws_size,
                              hipStream_t stream) {
  const float* x  = (const float*)d_in[0];
  // d_in[1] = adj: dead code in the reference, never read
  const float* Wq = (const float*)d_in[2];
  const float* Wk = (const float*)d_in[3];
  const float* Wv = (const float*)d_in[4];
  const float* Cw = (const float*)d_in[5];
  const float* cb = (const float*)d_in[6];
  const float* lw = (const float*)d_in[7];
  const float* lb = (const float*)d_in[8];
  float* out = (float*)d_out;
  char* ws = (char*)d_ws;
  short* xb = (short*)(ws);                         // 8192*256 bf16      = 4,194,304 B
  short* Wt = (short*)(ws + (size_t)4194304);       // 2048*256 bf16     = 1,048,576 B
  short* Qw = (short*)(ws + (size_t)5242880);       // 8*8*1024*64 bf16  = 8,388,608 B
  short* Kw = (short*)(ws + (size_t)13631488);
  short* Vt = (short*)(ws + (size_t)22020096);      // transposed V [B][H][64][N]
  short* Pj = (short*)(ws + (size_t)30408704);      // 8192*512 bf16
  short* At = (short*)(ws + (size_t)38797312);      // 8192*512 bf16  (end: 47,185,920 B)

  hipLaunchKernelGGL(k_prep, dim3(3072), dim3(256), 0, stream, Wq, Wk, Wv, Cw, x, Wt, xb);
  hipLaunchKernelGGL(k_gemm, dim3(1024), dim3(256), 0, stream, xb, Wt, Qw, Kw, Vt, Pj);
  hipLaunchKernelGGL(k_attn, dim3(256), dim3(256), 0, stream, Qw, Kw, Vt, At);
  hipLaunchKernelGGL(k_ln, dim3(2048), dim3(256), 0, stream, At, Pj, cb, lw, lb, out);
}

// Round 10
// 65.639 us; speedup vs baseline: 1.0746x; 1.0746x over previous
//
#include <hip/hip_runtime.h>

#define B_ 8
#define N_ 1024
#define CIN_ 256
#define COUT_ 512
#define H_ 8
#define DH_ 64

typedef __attribute__((ext_vector_type(8))) short bf8;
typedef __attribute__((ext_vector_type(4))) short s4;
typedef __attribute__((ext_vector_type(4))) float f4;
typedef __attribute__((ext_vector_type(2))) unsigned int u2;

__device__ __forceinline__ short f2bf(float f) {
  unsigned u = __builtin_bit_cast(unsigned, f);
  u += 0x7fffu + ((u >> 16) & 1u);
  return (short)(u >> 16);
}
__device__ __forceinline__ float bf2f(short s) {
  unsigned u = ((unsigned)(unsigned short)s) << 16;
  return __builtin_bit_cast(float, u);
}

#if __has_builtin(__builtin_amdgcn_exp2f)
#define EXP2 __builtin_amdgcn_exp2f
#else
#define EXP2 exp2f
#endif

__device__ __forceinline__ unsigned cvtpk(float a, float b) {
  unsigned u;
  asm("v_cvt_pk_bf16_f32 %0, %1, %2" : "=v"(u) : "v"(a), "v"(b));
  return u;
}

#define MFMA16(a, b, c) __builtin_amdgcn_mfma_f32_16x16x32_bf16((a), (b), (c), 0, 0, 0)

// async 16B global->LDS (linear dest: wave-uniform base + lane*16)
#define GLD16(gp, lp)                                                              \
  __builtin_amdgcn_global_load_lds((const __attribute__((address_space(1))) void*)(gp), \
                                   (__attribute__((address_space(3))) void*)(lp), 16, 0, 0)

// ---- prep: Wt[2048][256] bf16 weight panel (Q|K|V|conv) + x cast, fused ----
__global__ void k_prep(const float* __restrict__ Wq, const float* __restrict__ Wk,
                       const float* __restrict__ Wv, const float* __restrict__ Cw,
                       const float* __restrict__ x, short* __restrict__ Wt,
                       short* __restrict__ xb) {
  int blk = blockIdx.x;
  if (blk < 2048) {
    int col = blk;
    int k = threadIdx.x;
    float v;
    if (col < 512) {
      int h = col >> 6, d = col & 63;
      v = Wq[(h * CIN_ + k) * DH_ + d];
    } else if (col < 1024) {
      int c = col - 512, h = c >> 6, d = c & 63;
      v = Wk[(h * CIN_ + k) * DH_ + d];
    } else if (col < 1536) {
      int c = col - 1024, h = c >> 6, d = c & 63;
      v = Wv[(h * CIN_ + k) * DH_ + d];
    } else {
      v = Cw[(col - 1536) * CIN_ + k];
    }
    Wt[col * CIN_ + k] = f2bf(v);
  } else {
    int i = (blk - 2048) * 256 + threadIdx.x;
    f4 a = *reinterpret_cast<const f4*>(x + (size_t)i * 8);
    f4 b = *reinterpret_cast<const f4*>(x + (size_t)i * 8 + 4);
    bf8 o;
    o[0] = f2bf(a[0]); o[1] = f2bf(a[1]); o[2] = f2bf(a[2]); o[3] = f2bf(a[3]);
    o[4] = f2bf(b[0]); o[5] = f2bf(b[1]); o[6] = f2bf(b[2]); o[7] = f2bf(b[3]);
    *reinterpret_cast<bf8*>(xb + (size_t)i * 8) = o;
  }
}

// ---- GEMM: [8192x256] x [256x2048], 128x128 tile, BK=64, global_load_lds dbuf staging,
//      counted vmcnt + raw barriers, XOR-swizzled LDS.
//      Outputs: Q*scale, K ([B][H][N][64]), Vt ([B][H][64][N]), proj bf16 ----
__global__ __launch_bounds__(256) void k_gemm(const short* __restrict__ xb, const short* __restrict__ Wt,
                                              short* __restrict__ Qw, short* __restrict__ Kw,
                                              short* __restrict__ Vt, short* __restrict__ Pj) {
  __shared__ short Al[2][128][64];   // 32 KB: [buf][row][k], chunk c holds global chunk c^(row&7)
  __shared__ short Bl[2][128][64];   // 32 KB
  int tid = threadIdx.x;
  int mt = blockIdx.x >> 4, nt = blockIdx.x & 15;
  int row0 = mt * 128, col0 = nt * 128;
  int w = tid >> 6, lane = tid & 63, g = lane >> 4, lr = lane & 15;
  int wm = w >> 1, wn = w & 1;
  f4 acc[4][4];
#pragma unroll
  for (int i = 0; i < 4; ++i)
#pragma unroll
    for (int j = 0; j < 4; ++j) acc[i][j] = (f4){0.f, 0.f, 0.f, 0.f};

  // staging: per matrix 1024 16B-slots/tile; thread covers slots p*256+tid (p=0..3).
  // slot s -> row s>>3, lds chunk s&7, global chunk (s&7)^(row&7).
  int srow[4], sgc[4];
#pragma unroll
  for (int p = 0; p < 4; ++p) {
    int s = p * 256 + tid;
    srow[p] = s >> 3;
    sgc[p] = (s & 7) ^ (srow[p] & 7);
  }

#define STAGE_AB(k0_, buf_)                                                     \
  {                                                                             \
    char* abase = (char*)&Al[buf_][0][0];                                       \
    char* bbase = (char*)&Bl[buf_][0][0];                                       \
    _Pragma("unroll")                                                           \
    for (int p = 0; p < 4; ++p) {                                               \
      int lb = (p * 256 + w * 64) << 4;                                         \
      GLD16(xb + (row0 + srow[p]) * CIN_ + (k0_) + sgc[p] * 8, abase + lb);     \
      GLD16(Wt + (col0 + srow[p]) * CIN_ + (k0_) + sgc[p] * 8, bbase + lb);     \
    }                                                                           \
  }

  STAGE_AB(0, 0);

  for (int kt = 0; kt < 4; ++kt) {
    int cur = kt & 1;
    if (kt < 3) {
      STAGE_AB((kt + 1) * 64, cur ^ 1);
      asm volatile("s_waitcnt vmcnt(8)" ::: "memory");  // tile kt landed; kt+1's 8 stay out
    } else {
      asm volatile("s_waitcnt vmcnt(0)" ::: "memory");
    }
    __builtin_amdgcn_s_barrier();

    const short* al = &Al[cur][0][0];
    const short* bl = &Bl[cur][0][0];
    bf8 af[4][2], bb[4][2];
#pragma unroll
    for (int mi = 0; mi < 4; ++mi) {
      int R = wm * 64 + mi * 16 + lr;
      int sw = R & 7;
      af[mi][0] = *reinterpret_cast<const bf8*>(al + R * 64 + ((g ^ sw) * 8));
      af[mi][1] = *reinterpret_cast<const bf8*>(al + R * 64 + (((4 + g) ^ sw) * 8));
    }
#pragma unroll
    for (int ni = 0; ni < 4; ++ni) {
      int R = wn * 64 + ni * 16 + lr;
      int sw = R & 7;
      bb[ni][0] = *reinterpret_cast<const bf8*>(bl + R * 64 + ((g ^ sw) * 8));
      bb[ni][1] = *reinterpret_cast<const bf8*>(bl + R * 64 + (((4 + g) ^ sw) * 8));
    }
#pragma unroll
    for (int mi = 0; mi < 4; ++mi)
#pragma unroll
      for (int ni = 0; ni < 4; ++ni) {
        acc[mi][ni] = MFMA16(af[mi][0], bb[ni][0], acc[mi][ni]);
        acc[mi][ni] = MFMA16(af[mi][1], bb[ni][1], acc[mi][ni]);
      }
    asm volatile("s_waitcnt lgkmcnt(0)" ::: "memory");
    __builtin_amdgcn_s_barrier();   // all waves done reading buf cur before it is re-staged
  }

  const float QSCL = 0.125f * 1.4426950408889634f;  // 1/sqrt(dh) * log2(e), folded into Q
#pragma unroll
  for (int mi = 0; mi < 4; ++mi)
#pragma unroll
    for (int ni = 0; ni < 4; ++ni) {
      int c = col0 + wn * 64 + ni * 16 + lr;
      int r0 = row0 + wm * 64 + mi * 16 + g * 4;
      int b = r0 >> 10, n0 = r0 & 1023;
      if (c < 1024) {
#pragma unroll
        for (int j = 0; j < 4; ++j) {
          int n = n0 + j;
          if (c < 512) {
            Qw[((b * H_ + (c >> 6)) * N_ + n) * DH_ + (c & 63)] = f2bf(acc[mi][ni][j] * QSCL);
          } else {
            int cc = c - 512;
            Kw[((b * H_ + (cc >> 6)) * N_ + n) * DH_ + (cc & 63)] = f2bf(acc[mi][ni][j]);
          }
        }
      } else if (c < 1536) {
        int cc = c - 1024;
        int hh = cc >> 6, d = cc & 63;
        s4 vv;
#pragma unroll
        for (int j = 0; j < 4; ++j) vv[j] = f2bf(acc[mi][ni][j]);
        *reinterpret_cast<s4*>(Vt + ((size_t)(b * H_ + hh) * DH_ + d) * N_ + n0) = vv;
      } else {
#pragma unroll
        for (int j = 0; j < 4; ++j) {
          Pj[(size_t)(r0 + j) * COUT_ + (c - 1536)] = f2bf(acc[mi][ni][j]);
        }
      }
    }
}

// ---- attention: block = (b,h,128 q-rows), 4 waves x 32 q (qs=2). K/V in a RING-4 of LDS
//      buffers staged 2 tiles ahead via global_load_lds + counted vmcnt -> ONE barrier/tile.
//      Streaming softmax (no max), swapped QK, setprio around MFMA clusters. ----
__global__ __launch_bounds__(256) void k_attn(const short* __restrict__ Qw, const short* __restrict__ Kw,
                                              const short* __restrict__ Vt, short* __restrict__ At) {
  __shared__ short Kl[4][64][64];      // 32 KB ring: [buf][kv][dh], chunk c holds global chunk c^(kv&7)
  __shared__ short Vl[4][64][64];      // 32 KB ring: [buf][dh][kv], chunk c holds global chunk c^(dh&7)
  __shared__ short Pl[4][2][16][64];   // 16 KB: per-wave P relayout, XOR-swizzled cols
  int tid = threadIdx.x;
  // XCD swizzle: 512 blocks, 8 XCDs -> 64 consecutive nid per XCD = 8 full (b,h) groups
  int nid = ((blockIdx.x & 7) << 6) | (blockIdx.x >> 3);
  int bh = nid >> 3;
  int qb = nid & 7;
  int w = tid >> 6, lane = tid & 63, g = lane >> 4, lr = lane & 15;
  int qglob = qb * 128 + w * 32;
  const short* Qp = Qw + ((size_t)bh * N_ + qglob) * DH_;
  const short* Kp = Kw + (size_t)bh * N_ * DH_;
  const short* Vp = Vt + (size_t)bh * DH_ * N_;

  // staging geometry: 512 16B-slots per tile per matrix; slot s -> row s>>3, lds chunk s&7,
  // global chunk (s&7)^(row&7). Thread covers slots tid and tid+256.
  int sr0 = tid >> 3, sc0 = (tid & 7) ^ (sr0 & 7);
  int s1 = tid + 256;
  int sr1 = s1 >> 3, sc1 = (s1 & 7) ^ (sr1 & 7);
  int lo0 = (w * 64) << 4;           // wave-uniform LDS byte base, pass 0
  int lo1 = (w * 64 + 256) << 4;     // pass 1

#define STAGE_KV(tt_, buf_)                                                     \
  {                                                                             \
    const short* kb = Kp + (tt_) * (64 * DH_);                                  \
    const short* vb = Vp + (tt_) * 64;                                          \
    char* klb = (char*)&Kl[buf_][0][0];                                         \
    char* vlb = (char*)&Vl[buf_][0][0];                                         \
    GLD16(kb + sr0 * 64 + sc0 * 8, klb + lo0);                                  \
    GLD16(kb + sr1 * 64 + sc1 * 8, klb + lo1);                                  \
    GLD16(vb + (size_t)sr0 * N_ + sc0 * 8, vlb + lo0);                          \
    GLD16(vb + (size_t)sr1 * N_ + sc1 * 8, vlb + lo1);                          \
  }

  // prologue: stage tiles 0 and 1 into ring slots 0,1
  STAGE_KV(0, 0);
  STAGE_KV(1, 1);

  bf8 aq[2][2];
#pragma unroll
  for (int qs = 0; qs < 2; ++qs) {
    aq[qs][0] = *reinterpret_cast<const bf8*>(Qp + (qs * 16 + lr) * DH_ + g * 8);
    aq[qs][1] = *reinterpret_cast<const bf8*>(Qp + (qs * 16 + lr) * DH_ + 32 + g * 8);
  }

  f4 o[2][4];
  f4 lacc[2];
#pragma unroll
  for (int qs = 0; qs < 2; ++qs) {
    lacc[qs] = (f4){0.f, 0.f, 0.f, 0.f};
#pragma unroll
    for (int i = 0; i < 4; ++i) o[qs][i] = (f4){0.f, 0.f, 0.f, 0.f};
  }

  const int swz = (lr & 7) << 3;
  short* pl0 = &Pl[w][0][0][0];
  short* pl1 = &Pl[w][1][0][0];

  for (int t = 0; t < 16; ++t) {
    int cur = t & 3;
    if (t < 14) {
      // stage tile t+2 into ring slot (t+2)&3. Safe: every wave issuing this has passed
      // barrier(t-1), which proves all waves finished reading tile t-2 (same slot).
      STAGE_KV(t + 2, (t + 2) & 3);
      asm volatile("s_waitcnt vmcnt(8)" ::: "memory");   // tile t's 4 landed; t+1,t+2's 8 stay out
    } else if (t == 14) {
      asm volatile("s_waitcnt vmcnt(4)" ::: "memory");
    } else {
      asm volatile("s_waitcnt vmcnt(0)" ::: "memory");
    }
    __builtin_amdgcn_s_barrier();   // the ONLY barrier per tile

    // QK^T (swapped): D[kv][q], lane: q=lr, kv=kt*16+g*4+j
    const short* klc = &Kl[cur][0][0];
    bf8 bk0[4], bk1[4];
#pragma unroll
    for (int kt = 0; kt < 4; ++kt) {
      int R = kt * 16 + lr;
      const short* kr = klc + R * 64;
      int sw = (R & 7) << 3;
      bk0[kt] = *reinterpret_cast<const bf8*>(kr + ((g * 8) ^ sw));
      bk1[kt] = *reinterpret_cast<const bf8*>(kr + ((32 + g * 8) ^ sw));
    }
    f4 s0[4], s1v[4];
    __builtin_amdgcn_s_setprio(1);
#pragma unroll
    for (int kt = 0; kt < 4; ++kt) {
      f4 z = (f4){0.f, 0.f, 0.f, 0.f};
      z = MFMA16(bk0[kt], aq[0][0], z);
      z = MFMA16(bk1[kt], aq[0][1], z);
      s0[kt] = z;
      f4 z2 = (f4){0.f, 0.f, 0.f, 0.f};
      z2 = MFMA16(bk0[kt], aq[1][0], z2);
      z2 = MFMA16(bk1[kt], aq[1][1], z2);
      s1v[kt] = z2;
    }
    __builtin_amdgcn_s_setprio(0);
    // p = 2^s; accumulate l; pack bf16; write P rows (b64, swizzled)
#pragma unroll
    for (int kt = 0; kt < 4; ++kt) {
      f4 p;
      p[0] = EXP2(s0[kt][0]); p[1] = EXP2(s0[kt][1]);
      p[2] = EXP2(s0[kt][2]); p[3] = EXP2(s0[kt][3]);
      lacc[0] += p;
      u2 pk;
      pk[0] = cvtpk(p[0], p[1]);
      pk[1] = cvtpk(p[2], p[3]);
      *reinterpret_cast<u2*>(pl0 + lr * 64 + ((kt * 16 + g * 4) ^ swz)) = pk;
    }
#pragma unroll
    for (int kt = 0; kt < 4; ++kt) {
      f4 p;
      p[0] = EXP2(s1v[kt][0]); p[1] = EXP2(s1v[kt][1]);
      p[2] = EXP2(s1v[kt][2]); p[3] = EXP2(s1v[kt][3]);
      lacc[1] += p;
      u2 pk;
      pk[0] = cvtpk(p[0], p[1]);
      pk[1] = cvtpk(p[2], p[3]);
      *reinterpret_cast<u2*>(pl1 + lr * 64 + ((kt * 16 + g * 4) ^ swz)) = pk;
    }
    asm volatile("s_waitcnt lgkmcnt(0)" ::: "memory");
    __builtin_amdgcn_sched_barrier(0);
    bf8 pa00 = *reinterpret_cast<const bf8*>(pl0 + lr * 64 + ((g * 8) ^ swz));
    bf8 pa01 = *reinterpret_cast<const bf8*>(pl0 + lr * 64 + ((32 + g * 8) ^ swz));
    bf8 pa10 = *reinterpret_cast<const bf8*>(pl1 + lr * 64 + ((g * 8) ^ swz));
    bf8 pa11 = *reinterpret_cast<const bf8*>(pl1 + lr * 64 + ((32 + g * 8) ^ swz));
    // V frags from LDS + PV
    const short* vlc = &Vl[cur][0][0];
#pragma unroll
    for (int dt = 0; dt < 4; ++dt) {
      int R = dt * 16 + lr;
      const short* vr = vlc + R * 64;
      int sw = (R & 7) << 3;
      bf8 bv0 = *reinterpret_cast<const bf8*>(vr + ((g * 8) ^ sw));
      bf8 bv1 = *reinterpret_cast<const bf8*>(vr + ((32 + g * 8) ^ sw));
      __builtin_amdgcn_s_setprio(1);
      o[0][dt] = MFMA16(pa00, bv0, o[0][dt]);
      o[0][dt] = MFMA16(pa01, bv1, o[0][dt]);
      o[1][dt] = MFMA16(pa10, bv0, o[1][dt]);
      o[1][dt] = MFMA16(pa11, bv1, o[1][dt]);
      __builtin_amdgcn_s_setprio(0);
    }
    // per-wave Pl WAR safety for next tile (in-order DS pipe + drained queue); no block barrier
    asm volatile("s_waitcnt lgkmcnt(0)" ::: "memory");
  }

  // l: in-lane hsum + across the 4 g-copies -> full sum over kv for q=lr
  float ls[2];
#pragma unroll
  for (int qs = 0; qs < 2; ++qs) {
    float v = (lacc[qs][0] + lacc[qs][1]) + (lacc[qs][2] + lacc[qs][3]);
    v += __shfl_xor(v, 16, 64);
    v += __shfl_xor(v, 32, 64);
    ls[qs] = v;
  }
  // redistribute: lane needs l[q=g*4+j], held (replicated) by lane g*16 + g*4 + j
  float lf[2][4];
#pragma unroll
  for (int qs = 0; qs < 2; ++qs)
#pragma unroll
    for (int j = 0; j < 4; ++j)
      lf[qs][j] = __shfl(ls[qs], (lane & 48) + ((lane & 48) >> 2) + j, 64);
  int b = bh >> 3, h = bh & 7;
#pragma unroll
  for (int qs = 0; qs < 2; ++qs)
#pragma unroll
    for (int dt = 0; dt < 4; ++dt)
#pragma unroll
      for (int j = 0; j < 4; ++j) {
        float v = fmaxf(o[qs][dt][j] / lf[qs][j], 0.f);
        int n = qglob + qs * 16 + g * 4 + j;
        At[((size_t)b * N_ + n) * COUT_ + h * DH_ + dt * 16 + lr] = f2bf(v);
      }
}

// ---- add + bias + LayerNorm, f32 out ----
__global__ __launch_bounds__(256) void k_ln(const short* __restrict__ At, const short* __restrict__ Pj,
                                            const float* __restrict__ cb, const float* __restrict__ lw,
                                            const float* __restrict__ lb, float* __restrict__ out) {
  int row = blockIdx.x * 4 + (threadIdx.x >> 6);
  int lane = threadIdx.x & 63;
  int c0 = lane * 8;
  bf8 a8 = *reinterpret_cast<const bf8*>(At + (size_t)row * COUT_ + c0);
  bf8 p8 = *reinterpret_cast<const bf8*>(Pj + (size_t)row * COUT_ + c0);
  float y[8];
  float sum = 0.f, sq = 0.f;
#pragma unroll
  for (int j = 0; j < 8; ++j) {
    float v = bf2f(a8[j]) + bf2f(p8[j]) + cb[c0 + j];
    y[j] = v;
    sum += v;
    sq += v * v;
  }
#pragma unroll
  for (int off = 1; off < 64; off <<= 1) {
    sum += __shfl_xor(sum, off, 64);
    sq += __shfl_xor(sq, off, 64);
  }
  float mean = sum * (1.f / 512.f);
  float var = sq * (1.f / 512.f) - mean * mean;
  float rstd = rsqrtf(var + 1e-5f);
  f4 o0, o1;
#pragma unroll
  for (int j = 0; j < 4; ++j) o0[j] = (y[j] - mean) * rstd * lw[c0 + j] + lb[c0 + j];
#pragma unroll
  for (int j = 0; j < 4; ++j) o1[j] = (y[4 + j] - mean) * rstd * lw[c0 + 4 + j] + lb[c0 + 4 + j];
  *reinterpret_cast<f4*>(out + (size_t)row * COUT_ + c0) = o0;
  *reinterpret_cast<f4*>(out + (size_t)row * COUT_ + c0 + 4) = o1;
}

extern "C" void kernel_launch(void* const* d_in, const int* in_sizes, int n_in,
                              void* d_out, int out_size, void* d_ws, size_t ws_size,
                              hipStream_t stream) {
  const float* x  = (const float*)d_in[0];
  // d_in[1] = adj: dead code in the reference, never read
  const float* Wq = (const float*)d_in[2];
  const float* Wk = (const float*)d_in[3];
  const float* Wv = (const float*)d_in[4];
  const float* Cw = (const float*)d_in[5];
  const float* cb = (const float*)d_in[6];
  const float* lw = (const float*)d_in[7];
  const float* lb = (const float*)d_in[8];
  float* out = (float*)d_out;
  char* ws = (char*)d_ws;
  short* xb = (short*)(ws);                         // 8192*256 bf16      = 4,194,304 B
  short* Wt = (short*)(ws + (size_t)4194304);       // 2048*256 bf16     = 1,048,576 B
  short* Qw = (short*)(ws + (size_t)5242880);       // 8*8*1024*64 bf16  = 8,388,608 B
  short* Kw = (short*)(ws + (size_t)13631488);
  short* Vt = (short*)(ws + (size_t)22020096);      // transposed V [B][H][64][N]
  short* Pj = (short*)(ws + (size_t)30408704);      // 8192*512 bf16
  short* At = (short*)(ws + (size_t)38797312);      // 8192*512 bf16  (end: 47,185,920 B)

  hipLaunchKernelGGL(k_prep, dim3(3072), dim3(256), 0, stream, Wq, Wk, Wv, Cw, x, Wt, xb);
  hipLaunchKernelGGL(k_gemm, dim3(1024), dim3(256), 0, stream, xb, Wt, Qw, Kw, Vt, Pj);
  hipLaunchKernelGGL(k_attn, dim3(512), dim3(256), 0, stream, Qw, Kw, Vt, At);
  hipLaunchKernelGGL(k_ln, dim3(2048), dim3(256), 0, stream, At, Pj, cb, lw, lb, out);
}